// Round 1
// baseline (964.652 us; speedup 1.0000x reference)
//
#include <hip/hip_runtime.h>

#define ESP 1e-12f

// Kernel 1: one block per row. Row = 8192 floats from p and g.
// 256 threads x 8 float4 iterations per input, coalesced 16B/lane.
__global__ __launch_bounds__(256) void row_loss_kernel(
    const float* __restrict__ p,
    const float* __restrict__ g,
    float* __restrict__ row_loss,
    int C) {
    const int row = blockIdx.x;
    const float4* p4 = (const float4*)(p + (size_t)row * C);
    const float4* g4 = (const float4*)(g + (size_t)row * C);
    const int n4 = C >> 2;  // 2048 float4 per row

    float sum = 0.0f;
    float cnt = 0.0f;

    for (int i = threadIdx.x; i < n4; i += 256) {
        float4 pv = p4[i];
        float4 gv = g4[i];

        {
            float m = (gv.x != 0.0f) ? 1.0f : 0.0f;
            float l = 1.0f - sqrtf(pv.x * gv.x + ESP)
                           - sqrtf((1.0f - pv.x) * (1.0f - gv.x) + ESP);
            sum += m * l; cnt += m;
        }
        {
            float m = (gv.y != 0.0f) ? 1.0f : 0.0f;
            float l = 1.0f - sqrtf(pv.y * gv.y + ESP)
                           - sqrtf((1.0f - pv.y) * (1.0f - gv.y) + ESP);
            sum += m * l; cnt += m;
        }
        {
            float m = (gv.z != 0.0f) ? 1.0f : 0.0f;
            float l = 1.0f - sqrtf(pv.z * gv.z + ESP)
                           - sqrtf((1.0f - pv.z) * (1.0f - gv.z) + ESP);
            sum += m * l; cnt += m;
        }
        {
            float m = (gv.w != 0.0f) ? 1.0f : 0.0f;
            float l = 1.0f - sqrtf(pv.w * gv.w + ESP)
                           - sqrtf((1.0f - pv.w) * (1.0f - gv.w) + ESP);
            sum += m * l; cnt += m;
        }
    }

    // wave-64 butterfly reduce
    #pragma unroll
    for (int off = 32; off > 0; off >>= 1) {
        sum += __shfl_down(sum, off, 64);
        cnt += __shfl_down(cnt, off, 64);
    }

    __shared__ float s_sum[4];
    __shared__ float s_cnt[4];
    const int wave = threadIdx.x >> 6;
    const int lane = threadIdx.x & 63;
    if (lane == 0) { s_sum[wave] = sum; s_cnt[wave] = cnt; }
    __syncthreads();

    if (threadIdx.x == 0) {
        float ts = s_sum[0] + s_sum[1] + s_sum[2] + s_sum[3];
        float tc = s_cnt[0] + s_cnt[1] + s_cnt[2] + s_cnt[3];
        row_loss[row] = (tc > 0.0f) ? (ts / tc) : 0.0f;
    }
}

// Kernel 2: single block reduces B row losses -> scalar mean.
__global__ __launch_bounds__(1024) void final_reduce_kernel(
    const float* __restrict__ row_loss,
    float* __restrict__ out,
    int B) {
    float sum = 0.0f;
    for (int i = threadIdx.x; i < B; i += 1024) sum += row_loss[i];

    #pragma unroll
    for (int off = 32; off > 0; off >>= 1)
        sum += __shfl_down(sum, off, 64);

    __shared__ float s[16];
    const int wave = threadIdx.x >> 6;
    const int lane = threadIdx.x & 63;
    if (lane == 0) s[wave] = sum;
    __syncthreads();

    if (threadIdx.x == 0) {
        float total = 0.0f;
        #pragma unroll
        for (int w = 0; w < 16; w++) total += s[w];
        out[0] = total / (float)B;
    }
}

extern "C" void kernel_launch(void* const* d_in, const int* in_sizes, int n_in,
                              void* d_out, int out_size, void* d_ws, size_t ws_size,
                              hipStream_t stream) {
    const float* p = (const float*)d_in[0];
    const float* g = (const float*)d_in[1];
    float* out = (float*)d_out;
    float* row_loss = (float*)d_ws;  // B floats = 64 KB scratch

    const int C = 8192;
    const int B = in_sizes[0] / C;  // 16384

    row_loss_kernel<<<B, 256, 0, stream>>>(p, g, row_loss, C);
    final_reduce_kernel<<<1, 1024, 0, stream>>>(row_loss, out, B);
}